// Round 16
// baseline (185.244 us; speedup 1.0000x reference)
//
#include <hip/hip_runtime.h>
#include <hip/hip_bf16.h>

typedef __bf16 bf16x8_t __attribute__((ext_vector_type(8)));
typedef float f32x4_t __attribute__((ext_vector_type(4)));
using bf16 = __hip_bfloat16;

// Barrier WITHOUT vmcnt drain: LDS ops (lgkm) drained, but global register-
// destined prefetch loads stay in flight across the barrier (the compiler
// still inserts dep-driven vmcnt(N) at each use). This is the piece
// __syncthreads() (vmcnt(0) drain) structurally forbids.
__device__ __forceinline__ void softbar() {
  asm volatile("s_waitcnt lgkmcnt(0)\n\ts_barrier" ::: "memory");
}

__device__ __forceinline__ unsigned short f2bf_bits(float v) {
  __hip_bfloat16 h = __float2bfloat16(v);
  return *reinterpret_cast<unsigned short*>(&h);
}

// mish(x) = x*tanh(softplus(x)) = x*n/(n+2) with n = e^x*(e^x+2).
__device__ __forceinline__ float mish_f(float x) {
  float z = __expf(x);
  float n = z * (z + 2.0f);
  float m = x * n / (n + 2.0f);
  return (x > 10.0f) ? x : m;
}

// 13 cubic B-spline basis values (grid 10, k=3, [-2,2]) + mish -> 28B LDS region.
__device__ __forceinline__ void kan_feats28(bf16* dst, float x) {
  unsigned int* d32 = (unsigned int*)dst;
#pragma unroll
  for (int d = 0; d < 7; ++d) d32[d] = 0u;
  float t = (x + 3.2f) * 2.5f;
  if (t >= 0.0f && t < 16.0f) {
    float tf = floorf(t);
    int c = (int)tf;
    float u = t - tf;
    float um = 1.0f - u;
    float u2 = u * u, u3 = u2 * u;
    const float s6 = 1.0f / 6.0f;
    float w0 = um * um * um * s6;
    float w1 = (3.0f * u3 - 6.0f * u2 + 4.0f) * s6;
    float w2 = (-3.0f * u3 + 3.0f * u2 + 3.0f * u + 1.0f) * s6;
    float w3 = u3 * s6;
    int j0 = c - 3;
    if (j0 >= 0)               dst[j0]     = __float2bfloat16(w0);
    if (j0 >= -1 && j0 <= 11)  dst[j0 + 1] = __float2bfloat16(w1);
    if (j0 >= -2 && j0 <= 10)  dst[j0 + 2] = __float2bfloat16(w2);
    if (j0 <= 9)               dst[j0 + 3] = __float2bfloat16(w3);
  }
  dst[13] = __float2bfloat16(mish_f(x));
}

// Builds W1f, W2f, W3f — ALL MFMA-fragment-major. Frag s (global k-frag of 32)
// x ntg (group of 16 N-rows): 512 elements (1KB); element (n,quad,el) at
// (s*16+ntg)*512 + n*32 + quad*8 + el. k'=i*14+2d even -> bf16 pairs = dwords.
__global__ __launch_bounds__(256) void prep_all(
    const float* __restrict__ c1, const float* __restrict__ sb1, const float* __restrict__ sp1,
    const float* __restrict__ c2, const float* __restrict__ sb2, const float* __restrict__ sp2,
    const float* __restrict__ c3, const float* __restrict__ sb3, const float* __restrict__ sp3,
    bf16* __restrict__ W1f, bf16* __restrict__ W2f, bf16* __restrict__ W3f) {
  const int b = blockIdx.x, t = threadIdx.x;
  float vals[14];
  if (b < 49) {
    const int i = b, o = t;
    const int ntg = o >> 4, lrr = o & 15;
    const size_t io = (size_t)i * 256 + o;
    const float spv = sp1[io];
#pragma unroll
    for (int r = 0; r < 13; ++r) vals[r] = c1[io * 13 + r] * spv;
    vals[13] = sb1[io];
#pragma unroll
    for (int d = 0; d < 7; ++d) {
      const int k2 = i * 14 + 2 * d;
      const int s = k2 >> 5, r2 = k2 & 31;
      const size_t off = ((size_t)(s * 16 + ntg)) * 512 + lrr * 32 + (r2 >> 3) * 8 + (r2 & 7);
      *(unsigned int*)(W1f + off) = (unsigned int)f2bf_bits(vals[2 * d]) |
                                    ((unsigned int)f2bf_bits(vals[2 * d + 1]) << 16);
    }
  } else if (b == 49) {
    const int ntg = t >> 4, lrr = t & 15;
#pragma unroll
    for (int d = 0; d < 9; ++d) {
      const int k2 = 686 + 2 * d;
      const int r2 = k2 & 31;
      *(unsigned int*)(W1f + ((size_t)(21 * 16 + ntg)) * 512 + lrr * 32 + (r2 >> 3) * 8 + (r2 & 7)) = 0u;
    }
  } else if (b < 562) {
    if (t >= 128) return;
    const int idx = b - 50;
    const int i = idx >> 1;
    const int o = (idx & 1) * 128 + t;
    const int ntg = o >> 4, lrr = o & 15;
    const size_t io = (size_t)i * 256 + o;
    const float spv = sp2[io];
#pragma unroll
    for (int r = 0; r < 13; ++r) vals[r] = c2[io * 13 + r] * spv;
    vals[13] = sb2[io];
#pragma unroll
    for (int d = 0; d < 7; ++d) {
      const int k2 = i * 14 + 2 * d;
      const int s = k2 >> 5, r2 = k2 & 31;
      const size_t off = ((size_t)(s * 16 + ntg)) * 512 + lrr * 32 + (r2 >> 3) * 8 + (r2 & 7);
      *(unsigned int*)(W2f + off) = (unsigned int)f2bf_bits(vals[2 * d]) |
                                    ((unsigned int)f2bf_bits(vals[2 * d + 1]) << 16);
    }
  } else {
    const int i = b - 562, o = t;
    if (o < 10) {
      const size_t io = (size_t)i * 10 + o;
      const float spv = sp3[io];
#pragma unroll
      for (int r = 0; r < 13; ++r) vals[r] = c3[io * 13 + r] * spv;
      vals[13] = sb3[io];
#pragma unroll
      for (int d = 0; d < 7; ++d) {
        const int k2 = i * 14 + 2 * d;
        const int s = k2 >> 5, r2 = k2 & 31;
        const size_t off = (size_t)s * 512 + o * 32 + (r2 >> 3) * 8 + (r2 & 7);
        *(unsigned int*)(W3f + off) = (unsigned int)f2bf_bits(vals[2 * d]) |
                                      ((unsigned int)f2bf_bits(vals[2 * d + 1]) << 16);
      }
    } else if (o < 16) {
#pragma unroll
      for (int d = 0; d < 7; ++d) {
        const int k2 = i * 14 + 2 * d;
        const int s = k2 >> 5, r2 = k2 & 31;
        *(unsigned int*)(W3f + (size_t)s * 512 + o * 32 + (r2 >> 3) * 8 + (r2 & 7)) = 0u;
      }
    }
  }
}

// Megakernel v7: producer/consumer + soft barriers (cross-window register
// prefetch survives) + 32-input chunks for layers 2/3 (8 windows x 14 frags).
// A-tile stride 474 bf16: 13*lr mod 32 all-distinct -> b128 reads at the
// conflict-free 8-deep floor. Consumers (waves 0..7) own 32 cols; producers
// (waves 8..15) do only feats, 2 evals/window. Hs transposed [col][36].
__global__ __launch_bounds__(1024, 4) void meganet(
    const float* __restrict__ x, const bf16* __restrict__ W1f,
    const bf16* __restrict__ W2f, const bf16* __restrict__ W3f,
    const float* __restrict__ b1, const float* __restrict__ b2,
    const float* __restrict__ b3, float* __restrict__ out) {
  __shared__ __align__(16) char lds[104704];
  float* const Hs = (float*)lds;             // [256][36] f32 transposed
  bf16* const Ach0 = (bf16*)(lds + 36864);   // [32][474] bf16 = 30336B
  bf16* const Ach1 = (bf16*)(lds + 67200);   // 30336B
  float* const P = (float*)(lds + 97536);    // [32][56] f32
  float* const xs = (float*)lds;             // phase A only (50176B)
  float* const Red = (float*)(lds + 36864);  // [7][32][16] f32 (E tail)
  float* const V = (float*)(lds + 51200);    // 32x16 f32

  const int t = threadIdx.x;
  const int w = t >> 6, lane = t & 63, quad = lane >> 4, lr = lane & 15;
  const int tr = (t >> 4) & 31, ej = t & 15;  // producer eval coords (t>=512)
  const int r0 = blockIdx.x * 32;
  const int foff = lr * 32 + quad * 8;
  const bool cons = (w < 8);
  const int ntg0 = 2 * w;  // consumer col-group base (valid w<8)

  // ---- Phase A: pool 32 images -> P[32][56] ----
  for (int h = 0; h < 2; ++h) {
    const float4* src = (const float4*)x + (size_t)(r0 + h * 16) * 196;
    float4* xd = (float4*)xs;
#pragma unroll
    for (int l = 0; l < 4; ++l) {
      const int idx = t + l * 1024;
      if (idx < 3136) xd[idx] = src[idx];
    }
    softbar();
    if (t < 784) {
      const int img = t / 49, p = t - img * 49;
      const int oh = p / 7, ow = p - oh * 7;
      const float* xi = xs + img * 784 + oh * 112 + ow * 4;
      float s = 0.f;
#pragma unroll
      for (int rr = 0; rr < 4; ++rr)
#pragma unroll
        for (int cc = 0; cc < 4; ++cc) s += xi[rr * 28 + cc];
      P[(h * 16 + img) * 56 + p] = s * (1.0f / 16.0f);
    }
    softbar();
  }

  f32x4_t acc[2][2];
#pragma unroll
  for (int m = 0; m < 2; ++m)
#pragma unroll
    for (int n = 0; n < 2; ++n) acc[m][n] = (f32x4_t){0.f, 0.f, 0.f, 0.f};

  bf16x8_t q0[6], q1[6];

  // ---- Phase B: layer-1, K=704 (22 frags; windows of 16 inputs: 7,7,7,1) ----
  if (cons) {
#pragma unroll
    for (int s = 0; s < 4; ++s) {
      q0[s] = *(const bf16x8_t*)(W1f + (size_t)(s * 16 + ntg0) * 512 + foff);
      q1[s] = *(const bf16x8_t*)(W1f + (size_t)(s * 16 + ntg0 + 1) * 512 + foff);
    }
  } else {
    kan_feats28(Ach0 + tr * 474 + ej * 14, P[tr * 56 + ej]);  // chunk 0
  }
  softbar();
#pragma unroll
  for (int c = 0; c < 4; ++c) {
    const bf16* const Ac = (c & 1) ? Ach1 : Ach0;
    bf16* const An = (c & 1) ? Ach0 : Ach1;
    if (cons) {
      const int nks = (c < 3) ? 7 : 1;
#pragma unroll
      for (int ks = 0; ks < 7; ++ks) {
        if (ks >= nks) continue;
        const int kk = c * 7 + ks;
        const int sl = kk & 3;
        bf16x8_t bb0 = q0[sl], bb1 = q1[sl];
        if (kk + 4 < 22) {
          q0[sl] = *(const bf16x8_t*)(W1f + (size_t)((kk + 4) * 16 + ntg0) * 512 + foff);
          q1[sl] = *(const bf16x8_t*)(W1f + (size_t)((kk + 4) * 16 + ntg0 + 1) * 512 + foff);
        }
#pragma unroll
        for (int m = 0; m < 2; ++m) {
          bf16x8_t a = *(const bf16x8_t*)(Ac + (m * 16 + lr) * 474 + ks * 32 + quad * 8);
          acc[m][0] = __builtin_amdgcn_mfma_f32_16x16x32_bf16(a, bb0, acc[m][0], 0, 0, 0);
          acc[m][1] = __builtin_amdgcn_mfma_f32_16x16x32_bf16(a, bb1, acc[m][1], 0, 0, 0);
        }
      }
    } else {
      if (c < 2) {
        kan_feats28(An + tr * 474 + ej * 14, P[tr * 56 + (c + 1) * 16 + ej]);
      } else if (c == 2) {
        if (ej == 0) kan_feats28(An + tr * 474, P[tr * 56 + 48]);
        else if (ej == 1) {
          unsigned int* z = (unsigned int*)(An + tr * 474 + 14);
#pragma unroll
          for (int d = 0; d < 9; ++d) z[d] = 0u;  // pad k 686..703
        }
      }
    }
    softbar();
  }
  // H1 = acc + b1 -> Hs (transposed)
  if (cons) {
#pragma unroll
    for (int m = 0; m < 2; ++m)
#pragma unroll
      for (int n = 0; n < 2; ++n) {
        const int col = w * 32 + n * 16 + lr;
        const float bn = b1[col];
        f32x4_t v;
#pragma unroll
        for (int r = 0; r < 4; ++r) v[r] = acc[m][n][r] + bn;
        *(f32x4_t*)(Hs + col * 36 + m * 16 + quad * 4) = v;
      }
  }
  softbar();

  // ---- Phase C: layer-2, K=3584 (8 windows x 14 frags) ----
#pragma unroll
  for (int m = 0; m < 2; ++m)
#pragma unroll
    for (int n = 0; n < 2; ++n) acc[m][n] = (f32x4_t){0.f, 0.f, 0.f, 0.f};
  if (cons) {
#pragma unroll
    for (int s = 0; s < 6; ++s) {
      q0[s] = *(const bf16x8_t*)(W2f + (size_t)(s * 16 + ntg0) * 512 + foff);
      q1[s] = *(const bf16x8_t*)(W2f + (size_t)(s * 16 + ntg0 + 1) * 512 + foff);
    }
  } else {
    kan_feats28(Ach0 + tr * 474 + ej * 14, Hs[ej * 36 + tr]);
    kan_feats28(Ach0 + tr * 474 + (ej + 16) * 14, Hs[(ej + 16) * 36 + tr]);
  }
  softbar();
#pragma unroll
  for (int c = 0; c < 8; ++c) {
    const bf16* const Ac = (c & 1) ? Ach1 : Ach0;
    bf16* const An = (c & 1) ? Ach0 : Ach1;
    if (cons) {
#pragma unroll
      for (int j = 0; j < 14; ++j) {
        const int kk = c * 14 + j;
        const int sl = kk % 6;
        bf16x8_t bb0 = q0[sl], bb1 = q1[sl];
        if (kk + 6 < 112) {
          q0[sl] = *(const bf16x8_t*)(W2f + (size_t)((kk + 6) * 16 + ntg0) * 512 + foff);
          q1[sl] = *(const bf16x8_t*)(W2f + (size_t)((kk + 6) * 16 + ntg0 + 1) * 512 + foff);
        }
#pragma unroll
        for (int m = 0; m < 2; ++m) {
          bf16x8_t a = *(const bf16x8_t*)(Ac + (m * 16 + lr) * 474 + j * 32 + quad * 8);
          acc[m][0] = __builtin_amdgcn_mfma_f32_16x16x32_bf16(a, bb0, acc[m][0], 0, 0, 0);
          acc[m][1] = __builtin_amdgcn_mfma_f32_16x16x32_bf16(a, bb1, acc[m][1], 0, 0, 0);
        }
      }
    } else if (c < 7) {
      const int i0 = (c + 1) * 32 + ej;
      kan_feats28(An + tr * 474 + ej * 14, Hs[i0 * 36 + tr]);
      kan_feats28(An + tr * 474 + (ej + 16) * 14, Hs[(i0 + 16) * 36 + tr]);
    }
    softbar();
  }
  // H2 = acc + b2 -> Hs (overwrite; H1 dead)
  if (cons) {
#pragma unroll
    for (int m = 0; m < 2; ++m)
#pragma unroll
      for (int n = 0; n < 2; ++n) {
        const int col = w * 32 + n * 16 + lr;
        const float bn = b2[col];
        f32x4_t v;
#pragma unroll
        for (int r = 0; r < 4; ++r) v[r] = acc[m][n][r] + bn;
        *(f32x4_t*)(Hs + col * 36 + m * 16 + quad * 4) = v;
      }
  }
  softbar();

  // ---- Phase E: layer-3 (8 windows x 14 frags; consumers = waves 0..6,
  //      each owns ks {w, w+7} x both m-halves) ----
  f32x4_t acc3[2];
  acc3[0] = (f32x4_t){0.f, 0.f, 0.f, 0.f};
  acc3[1] = acc3[0];
  bf16x8_t q3[4];
  if (w < 7) {
#pragma unroll
    for (int cc = 0; cc < 2; ++cc) {
      q3[cc * 2] = *(const bf16x8_t*)(W3f + (size_t)(cc * 14 + w) * 512 + foff);
      q3[cc * 2 + 1] = *(const bf16x8_t*)(W3f + (size_t)(cc * 14 + 7 + w) * 512 + foff);
    }
  } else if (!cons) {
    kan_feats28(Ach0 + tr * 474 + ej * 14, Hs[ej * 36 + tr]);
    kan_feats28(Ach0 + tr * 474 + (ej + 16) * 14, Hs[(ej + 16) * 36 + tr]);
  }
  softbar();
#pragma unroll
  for (int c = 0; c < 8; ++c) {
    const bf16* const Ac = (c & 1) ? Ach1 : Ach0;
    bf16* const An = (c & 1) ? Ach0 : Ach1;
    if (w < 7) {
      const int p = (c & 1) * 2;
      bf16x8_t bb0 = q3[p], bb1 = q3[p + 1];
      if (c + 2 < 8) {
        q3[p] = *(const bf16x8_t*)(W3f + (size_t)((c + 2) * 14 + w) * 512 + foff);
        q3[p + 1] = *(const bf16x8_t*)(W3f + (size_t)((c + 2) * 14 + 7 + w) * 512 + foff);
      }
#pragma unroll
      for (int m = 0; m < 2; ++m) {
        bf16x8_t a0 = *(const bf16x8_t*)(Ac + (m * 16 + lr) * 474 + w * 32 + quad * 8);
        bf16x8_t a1 = *(const bf16x8_t*)(Ac + (m * 16 + lr) * 474 + (7 + w) * 32 + quad * 8);
        acc3[m] = __builtin_amdgcn_mfma_f32_16x16x32_bf16(a0, bb0, acc3[m], 0, 0, 0);
        acc3[m] = __builtin_amdgcn_mfma_f32_16x16x32_bf16(a1, bb1, acc3[m], 0, 0, 0);
      }
    } else if (!cons && c < 7) {
      const int i0 = (c + 1) * 32 + ej;
      kan_feats28(An + tr * 474 + ej * 14, Hs[i0 * 36 + tr]);
      kan_feats28(An + tr * 474 + (ej + 16) * 14, Hs[(i0 + 16) * 36 + tr]);
    }
    softbar();
  }
  if (w < 7) {
#pragma unroll
    for (int m = 0; m < 2; ++m)
#pragma unroll
      for (int r = 0; r < 4; ++r)
        Red[w * 512 + (m * 16 + quad * 4 + r) * 16 + lr] = acc3[m][r];
  }
  softbar();
  if (t < 512) {
    float s = (ej < 10) ? b3[ej] : 0.f;
#pragma unroll
    for (int ks = 0; ks < 7; ++ks) s += Red[ks * 512 + tr * 16 + ej];
    V[tr * 16 + ej] = s;
  }
  softbar();
  if (t < 32) {
    float vv[10];
#pragma unroll
    for (int o = 0; o < 10; ++o) vv[o] = V[t * 16 + o];
    float mx = vv[0];
#pragma unroll
    for (int o = 1; o < 10; ++o) mx = fmaxf(mx, vv[o]);
    float se = 0.f;
#pragma unroll
    for (int o = 0; o < 10; ++o) se += expf(vv[o] - mx);
    const float l = mx + logf(se);
#pragma unroll
    for (int o = 0; o < 10; ++o) out[(size_t)(r0 + t) * 10 + o] = vv[o] - l;
  }
}

extern "C" void kernel_launch(void* const* d_in, const int* in_sizes, int n_in,
                              void* d_out, int out_size, void* d_ws, size_t ws_size,
                              hipStream_t stream) {
  const float* x = (const float*)d_in[0];
  const float* coef1 = (const float*)d_in[1];
  const float* sb1 = (const float*)d_in[2];
  const float* sp1 = (const float*)d_in[3];
  const float* b1 = (const float*)d_in[4];
  const float* coef2 = (const float*)d_in[5];
  const float* sb2 = (const float*)d_in[6];
  const float* sp2 = (const float*)d_in[7];
  const float* b2 = (const float*)d_in[8];
  const float* coef3 = (const float*)d_in[9];
  const float* sb3 = (const float*)d_in[10];
  const float* sp3 = (const float*)d_in[11];
  const float* b3 = (const float*)d_in[12];
  float* out = (float*)d_out;

  char* ws = (char*)d_ws;
  bf16* W1f = (bf16*)ws;              // 22 frags x 16 ntg x 1KB = 360448 B
  bf16* W2f = (bf16*)(ws + 360448);   // 112 x 16 x 1KB = 1835008 B
  bf16* W3f = (bf16*)(ws + 2195456);  // 112 x 1KB = 114688 B

  prep_all<<<818, 256, 0, stream>>>(coef1, sb1, sp1, coef2, sb2, sp2,
                                    coef3, sb3, sp3, W1f, W2f, W3f);
  meganet<<<256, 1024, 0, stream>>>(x, W1f, W2f, W3f, b1, b2, b3, out);
}

// Round 17
// 164.799 us; speedup vs baseline: 1.1241x; 1.1241x over previous
//
#include <hip/hip_runtime.h>
#include <hip/hip_bf16.h>

typedef __bf16 bf16x8_t __attribute__((ext_vector_type(8)));
typedef float f32x4_t __attribute__((ext_vector_type(4)));
using bf16 = __hip_bfloat16;

__device__ __forceinline__ unsigned short f2bf_bits(float v) {
  __hip_bfloat16 h = __float2bfloat16(v);
  return *reinterpret_cast<unsigned short*>(&h);
}

// mish(x) = x*tanh(softplus(x)) = x*n/(n+2) with n = e^x*(e^x+2).
__device__ __forceinline__ float mish_f(float x) {
  float z = __expf(x);
  float n = z * (z + 2.0f);
  float m = x * n / (n + 2.0f);
  return (x > 10.0f) ? x : m;
}

// 13 cubic B-spline basis values (grid 10, k=3, [-2,2]) + mish -> 28B LDS region.
__device__ __forceinline__ void kan_feats28(bf16* dst, float x) {
  unsigned int* d32 = (unsigned int*)dst;
#pragma unroll
  for (int d = 0; d < 7; ++d) d32[d] = 0u;
  float t = (x + 3.2f) * 2.5f;
  if (t >= 0.0f && t < 16.0f) {
    float tf = floorf(t);
    int c = (int)tf;
    float u = t - tf;
    float um = 1.0f - u;
    float u2 = u * u, u3 = u2 * u;
    const float s6 = 1.0f / 6.0f;
    float w0 = um * um * um * s6;
    float w1 = (3.0f * u3 - 6.0f * u2 + 4.0f) * s6;
    float w2 = (-3.0f * u3 + 3.0f * u2 + 3.0f * u + 1.0f) * s6;
    float w3 = u3 * s6;
    int j0 = c - 3;
    if (j0 >= 0)               dst[j0]     = __float2bfloat16(w0);
    if (j0 >= -1 && j0 <= 11)  dst[j0 + 1] = __float2bfloat16(w1);
    if (j0 >= -2 && j0 <= 10)  dst[j0 + 2] = __float2bfloat16(w2);
    if (j0 <= 9)               dst[j0 + 3] = __float2bfloat16(w3);
  }
  dst[13] = __float2bfloat16(mish_f(x));
}

// Builds W1f, W2f, W3f — ALL MFMA-fragment-major. Frag s (global k-frag of 32)
// x ntg (group of 16 N-rows): 512 elements (1KB); element (n,quad,el) at
// (s*16+ntg)*512 + n*32 + quad*8 + el. k'=i*14+2d even -> bf16 pairs = dwords.
__global__ __launch_bounds__(256) void prep_all(
    const float* __restrict__ c1, const float* __restrict__ sb1, const float* __restrict__ sp1,
    const float* __restrict__ c2, const float* __restrict__ sb2, const float* __restrict__ sp2,
    const float* __restrict__ c3, const float* __restrict__ sb3, const float* __restrict__ sp3,
    bf16* __restrict__ W1f, bf16* __restrict__ W2f, bf16* __restrict__ W3f) {
  const int b = blockIdx.x, t = threadIdx.x;
  float vals[14];
  if (b < 49) {
    const int i = b, o = t;
    const int ntg = o >> 4, lrr = o & 15;
    const size_t io = (size_t)i * 256 + o;
    const float spv = sp1[io];
#pragma unroll
    for (int r = 0; r < 13; ++r) vals[r] = c1[io * 13 + r] * spv;
    vals[13] = sb1[io];
#pragma unroll
    for (int d = 0; d < 7; ++d) {
      const int k2 = i * 14 + 2 * d;
      const int s = k2 >> 5, r2 = k2 & 31;
      const size_t off = ((size_t)(s * 16 + ntg)) * 512 + lrr * 32 + (r2 >> 3) * 8 + (r2 & 7);
      *(unsigned int*)(W1f + off) = (unsigned int)f2bf_bits(vals[2 * d]) |
                                    ((unsigned int)f2bf_bits(vals[2 * d + 1]) << 16);
    }
  } else if (b == 49) {
    const int ntg = t >> 4, lrr = t & 15;
#pragma unroll
    for (int d = 0; d < 9; ++d) {
      const int k2 = 686 + 2 * d;
      const int r2 = k2 & 31;
      *(unsigned int*)(W1f + ((size_t)(21 * 16 + ntg)) * 512 + lrr * 32 + (r2 >> 3) * 8 + (r2 & 7)) = 0u;
    }
  } else if (b < 562) {
    if (t >= 128) return;
    const int idx = b - 50;
    const int i = idx >> 1;
    const int o = (idx & 1) * 128 + t;
    const int ntg = o >> 4, lrr = o & 15;
    const size_t io = (size_t)i * 256 + o;
    const float spv = sp2[io];
#pragma unroll
    for (int r = 0; r < 13; ++r) vals[r] = c2[io * 13 + r] * spv;
    vals[13] = sb2[io];
#pragma unroll
    for (int d = 0; d < 7; ++d) {
      const int k2 = i * 14 + 2 * d;
      const int s = k2 >> 5, r2 = k2 & 31;
      const size_t off = ((size_t)(s * 16 + ntg)) * 512 + lrr * 32 + (r2 >> 3) * 8 + (r2 & 7);
      *(unsigned int*)(W2f + off) = (unsigned int)f2bf_bits(vals[2 * d]) |
                                    ((unsigned int)f2bf_bits(vals[2 * d + 1]) << 16);
    }
  } else {
    const int i = b - 562, o = t;
    if (o < 10) {
      const size_t io = (size_t)i * 10 + o;
      const float spv = sp3[io];
#pragma unroll
      for (int r = 0; r < 13; ++r) vals[r] = c3[io * 13 + r] * spv;
      vals[13] = sb3[io];
#pragma unroll
      for (int d = 0; d < 7; ++d) {
        const int k2 = i * 14 + 2 * d;
        const int s = k2 >> 5, r2 = k2 & 31;
        const size_t off = (size_t)s * 512 + o * 32 + (r2 >> 3) * 8 + (r2 & 7);
        *(unsigned int*)(W3f + off) = (unsigned int)f2bf_bits(vals[2 * d]) |
                                      ((unsigned int)f2bf_bits(vals[2 * d + 1]) << 16);
      }
    } else if (o < 16) {
#pragma unroll
      for (int d = 0; d < 7; ++d) {
        const int k2 = i * 14 + 2 * d;
        const int s = k2 >> 5, r2 = k2 & 31;
        *(unsigned int*)(W3f + (size_t)s * 512 + o * 32 + (r2 >> 3) * 8 + (r2 & 7)) = 0u;
      }
    }
  }
}

// Megakernel v8: 512 blocks x 512 threads = 2 independent barrier domains per
// CU — when one block stalls at s_barrier, the other's waves issue. Block owns
// 16 rows end-to-end. Wave w (0..7) owns cols w*32..+31 (acc 1m x 2n = 8
// VGPRs); feats by t<256 (1 eval/window). Weights register-direct from
// frag-major L2-resident buffers (4-deep queue). Hs transposed [col][20].
__global__ __launch_bounds__(512, 4) void meganet(
    const float* __restrict__ x, const bf16* __restrict__ W1f,
    const bf16* __restrict__ W2f, const bf16* __restrict__ W3f,
    const float* __restrict__ b1, const float* __restrict__ b2,
    const float* __restrict__ b3, float* __restrict__ out) {
  __shared__ __align__(16) char lds[38912];
  float* const Hs = (float*)lds;             // [256][20] f32 = 20480B
  bf16* const Ach0 = (bf16*)(lds + 20480);   // [16][232] bf16 = 7424B
  bf16* const Ach1 = (bf16*)(lds + 27904);   // 7424B
  float* const P = (float*)(lds + 35328);    // [16][56] f32 = 3584B
  float* const xs = (float*)lds;             // 8 images = 25088B (phase A alias)
  float* const Red = (float*)(lds + 20480);  // [7][16][16] f32 = 7168B (E tail)
  float* const V = (float*)(lds + 27904);    // 16x16 f32 (E tail)

  const int t = threadIdx.x;
  const int w = t >> 6, lane = t & 63, quad = lane >> 4, lr = lane & 15;
  const int tr = (t >> 4) & 15, ej = t & 15;  // feats coords (t<256)
  const int r0 = blockIdx.x * 16;
  const int foff = lr * 32 + quad * 8;
  const int ntg0 = 2 * w;

  // ---- Phase A: pool 16 images -> P[16][56], 2 passes of 8 ----
  for (int h = 0; h < 2; ++h) {
    const float4* src = (const float4*)x + (size_t)(r0 + h * 8) * 196;
    float4* xd = (float4*)xs;
#pragma unroll
    for (int l = 0; l < 4; ++l) {
      const int idx = t + l * 512;
      if (idx < 1568) xd[idx] = src[idx];
    }
    __syncthreads();
    if (t < 392) {
      const int img = t / 49, p = t - img * 49;
      const int oh = p / 7, ow = p - oh * 7;
      const float* xi = xs + img * 784 + oh * 112 + ow * 4;
      float s = 0.f;
#pragma unroll
      for (int rr = 0; rr < 4; ++rr)
#pragma unroll
        for (int cc = 0; cc < 4; ++cc) s += xi[rr * 28 + cc];
      P[(h * 8 + img) * 56 + p] = s * (1.0f / 16.0f);
    }
    __syncthreads();
  }

  f32x4_t acc[2];
  acc[0] = (f32x4_t){0.f, 0.f, 0.f, 0.f};
  acc[1] = acc[0];
  bf16x8_t q0[4], q1[4];

  // ---- Phase B: layer-1, K=704 (22 frags; windows 7,7,7,1) ----
#pragma unroll
  for (int s = 0; s < 4; ++s) {
    q0[s] = *(const bf16x8_t*)(W1f + (size_t)(s * 16 + ntg0) * 512 + foff);
    q1[s] = *(const bf16x8_t*)(W1f + (size_t)(s * 16 + ntg0 + 1) * 512 + foff);
  }
  if (t < 256) kan_feats28(Ach0 + tr * 232 + ej * 14, P[tr * 56 + ej]);
  __syncthreads();
#pragma unroll
  for (int c = 0; c < 4; ++c) {
    const bf16* const Ac = (c & 1) ? Ach1 : Ach0;
    bf16* const An = (c & 1) ? Ach0 : Ach1;
    const int nks = (c < 3) ? 7 : 1;
#pragma unroll
    for (int ks = 0; ks < 7; ++ks) {
      if (ks >= nks) continue;
      const int kk = c * 7 + ks;
      const int sl = kk & 3;
      bf16x8_t bb0 = q0[sl], bb1 = q1[sl];
      if (kk + 4 < 22) {
        q0[sl] = *(const bf16x8_t*)(W1f + (size_t)((kk + 4) * 16 + ntg0) * 512 + foff);
        q1[sl] = *(const bf16x8_t*)(W1f + (size_t)((kk + 4) * 16 + ntg0 + 1) * 512 + foff);
      }
      bf16x8_t a = *(const bf16x8_t*)(Ac + lr * 232 + ks * 32 + quad * 8);
      acc[0] = __builtin_amdgcn_mfma_f32_16x16x32_bf16(a, bb0, acc[0], 0, 0, 0);
      acc[1] = __builtin_amdgcn_mfma_f32_16x16x32_bf16(a, bb1, acc[1], 0, 0, 0);
    }
    if (t < 256) {
      if (c < 2) {
        kan_feats28(An + tr * 232 + ej * 14, P[tr * 56 + (c + 1) * 16 + ej]);
      } else if (c == 2) {
        if (ej == 0) kan_feats28(An + tr * 232, P[tr * 56 + 48]);
        else if (ej == 1) {
          unsigned int* z = (unsigned int*)(An + tr * 232 + 14);
#pragma unroll
          for (int d = 0; d < 9; ++d) z[d] = 0u;  // pad k 686..703
        }
      }
    }
    __syncthreads();
  }
  // H1 = acc + b1 -> Hs (transposed [col][20]; 80B row stride keeps b128 align)
#pragma unroll
  for (int n = 0; n < 2; ++n) {
    const int col = w * 32 + n * 16 + lr;
    const float bn = b1[col];
    f32x4_t v;
#pragma unroll
    for (int r = 0; r < 4; ++r) v[r] = acc[n][r] + bn;
    *(f32x4_t*)(Hs + col * 20 + quad * 4) = v;
  }
  __syncthreads();

  // ---- Phase C: layer-2, K=3584 (16 windows x 7 frags) ----
  acc[0] = (f32x4_t){0.f, 0.f, 0.f, 0.f};
  acc[1] = acc[0];
#pragma unroll
  for (int s = 0; s < 4; ++s) {
    q0[s] = *(const bf16x8_t*)(W2f + (size_t)(s * 16 + ntg0) * 512 + foff);
    q1[s] = *(const bf16x8_t*)(W2f + (size_t)(s * 16 + ntg0 + 1) * 512 + foff);
  }
  if (t < 256) kan_feats28(Ach0 + tr * 232 + ej * 14, Hs[ej * 20 + tr]);
  __syncthreads();
#pragma unroll
  for (int c = 0; c < 16; ++c) {
    const bf16* const Ac = (c & 1) ? Ach1 : Ach0;
    bf16* const An = (c & 1) ? Ach0 : Ach1;
#pragma unroll
    for (int ks = 0; ks < 7; ++ks) {
      const int kk = c * 7 + ks;
      const int sl = kk & 3;
      bf16x8_t bb0 = q0[sl], bb1 = q1[sl];
      if (kk + 4 < 112) {
        q0[sl] = *(const bf16x8_t*)(W2f + (size_t)((kk + 4) * 16 + ntg0) * 512 + foff);
        q1[sl] = *(const bf16x8_t*)(W2f + (size_t)((kk + 4) * 16 + ntg0 + 1) * 512 + foff);
      }
      bf16x8_t a = *(const bf16x8_t*)(Ac + lr * 232 + ks * 32 + quad * 8);
      acc[0] = __builtin_amdgcn_mfma_f32_16x16x32_bf16(a, bb0, acc[0], 0, 0, 0);
      acc[1] = __builtin_amdgcn_mfma_f32_16x16x32_bf16(a, bb1, acc[1], 0, 0, 0);
    }
    if (t < 256 && c < 15)
      kan_feats28(An + tr * 232 + ej * 14, Hs[((c + 1) * 16 + ej) * 20 + tr]);
    __syncthreads();
  }
  // H2 = acc + b2 -> Hs (overwrite; H1 dead after chunk-15 feats)
#pragma unroll
  for (int n = 0; n < 2; ++n) {
    const int col = w * 32 + n * 16 + lr;
    const float bn = b2[col];
    f32x4_t v;
#pragma unroll
    for (int r = 0; r < 4; ++r) v[r] = acc[n][r] + bn;
    *(f32x4_t*)(Hs + col * 20 + quad * 4) = v;
  }
  __syncthreads();

  // ---- Phase E: layer-3 (16 windows x 7 frags; wave w<7 owns ks=w) ----
  f32x4_t acc3 = {0.f, 0.f, 0.f, 0.f};
  bf16x8_t q3[4];
  if (w < 7) {
#pragma unroll
    for (int s = 0; s < 4; ++s)
      q3[s] = *(const bf16x8_t*)(W3f + (size_t)(s * 7 + w) * 512 + foff);
  }
  if (t < 256) kan_feats28(Ach0 + tr * 232 + ej * 14, Hs[ej * 20 + tr]);
  __syncthreads();
#pragma unroll
  for (int c = 0; c < 16; ++c) {
    const bf16* const Ac = (c & 1) ? Ach1 : Ach0;
    bf16* const An = (c & 1) ? Ach0 : Ach1;
    if (w < 7) {
      bf16x8_t bb = q3[c & 3];
      if (c + 4 < 16)
        q3[c & 3] = *(const bf16x8_t*)(W3f + (size_t)((c + 4) * 7 + w) * 512 + foff);
      bf16x8_t a = *(const bf16x8_t*)(Ac + lr * 232 + w * 32 + quad * 8);
      acc3 = __builtin_amdgcn_mfma_f32_16x16x32_bf16(a, bb, acc3, 0, 0, 0);
    }
    if (t < 256 && c < 15)
      kan_feats28(An + tr * 232 + ej * 14, Hs[((c + 1) * 16 + ej) * 20 + tr]);
    __syncthreads();
  }
  if (w < 7) {
#pragma unroll
    for (int r = 0; r < 4; ++r)
      Red[w * 256 + (quad * 4 + r) * 16 + lr] = acc3[r];
  }
  __syncthreads();
  if (t < 256) {
    float s = (ej < 10) ? b3[ej] : 0.f;
#pragma unroll
    for (int ks = 0; ks < 7; ++ks) s += Red[ks * 256 + tr * 16 + ej];
    V[tr * 16 + ej] = s;
  }
  __syncthreads();
  if (t < 16) {
    float vv[10];
#pragma unroll
    for (int o = 0; o < 10; ++o) vv[o] = V[t * 16 + o];
    float mx = vv[0];
#pragma unroll
    for (int o = 1; o < 10; ++o) mx = fmaxf(mx, vv[o]);
    float se = 0.f;
#pragma unroll
    for (int o = 0; o < 10; ++o) se += expf(vv[o] - mx);
    const float l = mx + logf(se);
#pragma unroll
    for (int o = 0; o < 10; ++o) out[(size_t)(r0 + t) * 10 + o] = vv[o] - l;
  }
}

extern "C" void kernel_launch(void* const* d_in, const int* in_sizes, int n_in,
                              void* d_out, int out_size, void* d_ws, size_t ws_size,
                              hipStream_t stream) {
  const float* x = (const float*)d_in[0];
  const float* coef1 = (const float*)d_in[1];
  const float* sb1 = (const float*)d_in[2];
  const float* sp1 = (const float*)d_in[3];
  const float* b1 = (const float*)d_in[4];
  const float* coef2 = (const float*)d_in[5];
  const float* sb2 = (const float*)d_in[6];
  const float* sp2 = (const float*)d_in[7];
  const float* b2 = (const float*)d_in[8];
  const float* coef3 = (const float*)d_in[9];
  const float* sb3 = (const float*)d_in[10];
  const float* sp3 = (const float*)d_in[11];
  const float* b3 = (const float*)d_in[12];
  float* out = (float*)d_out;

  char* ws = (char*)d_ws;
  bf16* W1f = (bf16*)ws;              // 22 frags x 16 ntg x 1KB = 360448 B
  bf16* W2f = (bf16*)(ws + 360448);   // 112 x 16 x 1KB = 1835008 B
  bf16* W3f = (bf16*)(ws + 2195456);  // 112 x 1KB = 114688 B

  prep_all<<<818, 256, 0, stream>>>(coef1, sb1, sp1, coef2, sb2, sp2,
                                    coef3, sb3, sp3, W1f, W2f, W3f);
  meganet<<<512, 512, 0, stream>>>(x, W1f, W2f, W3f, b1, b2, b3, out);
}

// Round 18
// 138.717 us; speedup vs baseline: 1.3354x; 1.1880x over previous
//
#include <hip/hip_runtime.h>
#include <hip/hip_bf16.h>

typedef __bf16 bf16x8_t __attribute__((ext_vector_type(8)));
typedef float f32x4_t __attribute__((ext_vector_type(4)));
using bf16 = __hip_bfloat16;

__device__ __forceinline__ unsigned short f2bf_bits(float v) {
  __hip_bfloat16 h = __float2bfloat16(v);
  return *reinterpret_cast<unsigned short*>(&h);
}

// mish(x) = x*tanh(softplus(x)) = x*n/(n+2) with n = e^x*(e^x+2).
__device__ __forceinline__ float mish_f(float x) {
  float z = __expf(x);
  float n = z * (z + 2.0f);
  float m = x * n / (n + 2.0f);
  return (x > 10.0f) ? x : m;
}

// 13 cubic B-spline basis values (grid 10, k=3, [-2,2]) + mish -> 28B LDS region.
__device__ __forceinline__ void kan_feats28(bf16* dst, float x) {
  unsigned int* d32 = (unsigned int*)dst;
#pragma unroll
  for (int d = 0; d < 7; ++d) d32[d] = 0u;
  float t = (x + 3.2f) * 2.5f;
  if (t >= 0.0f && t < 16.0f) {
    float tf = floorf(t);
    int c = (int)tf;
    float u = t - tf;
    float um = 1.0f - u;
    float u2 = u * u, u3 = u2 * u;
    const float s6 = 1.0f / 6.0f;
    float w0 = um * um * um * s6;
    float w1 = (3.0f * u3 - 6.0f * u2 + 4.0f) * s6;
    float w2 = (-3.0f * u3 + 3.0f * u2 + 3.0f * u + 1.0f) * s6;
    float w3 = u3 * s6;
    int j0 = c - 3;
    if (j0 >= 0)               dst[j0]     = __float2bfloat16(w0);
    if (j0 >= -1 && j0 <= 11)  dst[j0 + 1] = __float2bfloat16(w1);
    if (j0 >= -2 && j0 <= 10)  dst[j0 + 2] = __float2bfloat16(w2);
    if (j0 <= 9)               dst[j0 + 3] = __float2bfloat16(w3);
  }
  dst[13] = __float2bfloat16(mish_f(x));
}

// Builds W1f, W2f, W3f — ALL MFMA-fragment-major. Frag s (global k-frag of 32)
// x ntg (group of 16 N-rows): 512 elements (1KB); element (n,quad,el) at
// (s*16+ntg)*512 + n*32 + quad*8 + el. k'=i*14+2d even -> bf16 pairs = dwords.
__global__ __launch_bounds__(256) void prep_all(
    const float* __restrict__ c1, const float* __restrict__ sb1, const float* __restrict__ sp1,
    const float* __restrict__ c2, const float* __restrict__ sb2, const float* __restrict__ sp2,
    const float* __restrict__ c3, const float* __restrict__ sb3, const float* __restrict__ sp3,
    bf16* __restrict__ W1f, bf16* __restrict__ W2f, bf16* __restrict__ W3f) {
  const int b = blockIdx.x, t = threadIdx.x;
  float vals[14];
  if (b < 49) {
    const int i = b, o = t;
    const int ntg = o >> 4, lrr = o & 15;
    const size_t io = (size_t)i * 256 + o;
    const float spv = sp1[io];
#pragma unroll
    for (int r = 0; r < 13; ++r) vals[r] = c1[io * 13 + r] * spv;
    vals[13] = sb1[io];
#pragma unroll
    for (int d = 0; d < 7; ++d) {
      const int k2 = i * 14 + 2 * d;
      const int s = k2 >> 5, r2 = k2 & 31;
      const size_t off = ((size_t)(s * 16 + ntg)) * 512 + lrr * 32 + (r2 >> 3) * 8 + (r2 & 7);
      *(unsigned int*)(W1f + off) = (unsigned int)f2bf_bits(vals[2 * d]) |
                                    ((unsigned int)f2bf_bits(vals[2 * d + 1]) << 16);
    }
  } else if (b == 49) {
    const int ntg = t >> 4, lrr = t & 15;
#pragma unroll
    for (int d = 0; d < 9; ++d) {
      const int k2 = 686 + 2 * d;
      const int r2 = k2 & 31;
      *(unsigned int*)(W1f + ((size_t)(21 * 16 + ntg)) * 512 + lrr * 32 + (r2 >> 3) * 8 + (r2 & 7)) = 0u;
    }
  } else if (b < 562) {
    if (t >= 128) return;
    const int idx = b - 50;
    const int i = idx >> 1;
    const int o = (idx & 1) * 128 + t;
    const int ntg = o >> 4, lrr = o & 15;
    const size_t io = (size_t)i * 256 + o;
    const float spv = sp2[io];
#pragma unroll
    for (int r = 0; r < 13; ++r) vals[r] = c2[io * 13 + r] * spv;
    vals[13] = sb2[io];
#pragma unroll
    for (int d = 0; d < 7; ++d) {
      const int k2 = i * 14 + 2 * d;
      const int s = k2 >> 5, r2 = k2 & 31;
      const size_t off = ((size_t)(s * 16 + ntg)) * 512 + lrr * 32 + (r2 >> 3) * 8 + (r2 & 7);
      *(unsigned int*)(W2f + off) = (unsigned int)f2bf_bits(vals[2 * d]) |
                                    ((unsigned int)f2bf_bits(vals[2 * d + 1]) << 16);
    }
  } else {
    const int i = b - 562, o = t;
    if (o < 10) {
      const size_t io = (size_t)i * 10 + o;
      const float spv = sp3[io];
#pragma unroll
      for (int r = 0; r < 13; ++r) vals[r] = c3[io * 13 + r] * spv;
      vals[13] = sb3[io];
#pragma unroll
      for (int d = 0; d < 7; ++d) {
        const int k2 = i * 14 + 2 * d;
        const int s = k2 >> 5, r2 = k2 & 31;
        const size_t off = (size_t)s * 512 + o * 32 + (r2 >> 3) * 8 + (r2 & 7);
        *(unsigned int*)(W3f + off) = (unsigned int)f2bf_bits(vals[2 * d]) |
                                      ((unsigned int)f2bf_bits(vals[2 * d + 1]) << 16);
      }
    } else if (o < 16) {
#pragma unroll
      for (int d = 0; d < 7; ++d) {
        const int k2 = i * 14 + 2 * d;
        const int s = k2 >> 5, r2 = k2 & 31;
        *(unsigned int*)(W3f + (size_t)s * 512 + o * 32 + (r2 >> 3) * 8 + (r2 & 7)) = 0u;
      }
    }
  }
}

// Megakernel v6 (best measured): producer/consumer wave specialization.
// 256 blocks x 1024 thr. Consumers (waves 0..7) own 32 cols each and do ALL
// MFMAs; producers (waves 8..15) do ONLY feats, computing chunk c+1 into the
// other A-buffer while consumers crunch chunk c. One barrier per chunk.
// Hs transposed [col][36]. Weights register-direct from frag-major buffers.
__global__ __launch_bounds__(1024, 4) void meganet(
    const float* __restrict__ x, const bf16* __restrict__ W1f,
    const bf16* __restrict__ W2f, const bf16* __restrict__ W3f,
    const float* __restrict__ b1, const float* __restrict__ b2,
    const float* __restrict__ b3, float* __restrict__ out) {
  __shared__ __align__(16) char lds[73728];
  float* const Hs = (float*)lds;             // [256][36] f32 transposed
  bf16* const Ach0 = (bf16*)(lds + 36864);   // [32][232] bf16
  bf16* const Ach1 = (bf16*)(lds + 51712);
  float* const P = (float*)(lds + 66560);    // [32][56] f32
  float* const xs = (float*)lds;             // phase A only (50176)
  float* const Red = (float*)(lds + 36864);  // [7][32][16] f32 (E tail)
  float* const V = (float*)(lds + 51712);    // 32x16 f32

  const int t = threadIdx.x;
  const int w = t >> 6, lane = t & 63, quad = lane >> 4, lr = lane & 15;
  const int tr = (t >> 4) & 31, ej = t & 15;  // producer eval coords (t>=512)
  const int r0 = blockIdx.x * 32;
  const int foff = lr * 32 + quad * 8;
  const bool cons = (w < 8);
  const int ntg0 = 2 * w;  // consumer col-group base (valid w<8)

  // ---- Phase A: pool 32 images -> P[32][56] ----
  for (int h = 0; h < 2; ++h) {
    const float4* src = (const float4*)x + (size_t)(r0 + h * 16) * 196;
    float4* xd = (float4*)xs;
#pragma unroll
    for (int l = 0; l < 4; ++l) {
      const int idx = t + l * 1024;
      if (idx < 3136) xd[idx] = src[idx];
    }
    __syncthreads();
    if (t < 784) {
      const int img = t / 49, p = t - img * 49;
      const int oh = p / 7, ow = p - oh * 7;
      const float* xi = xs + img * 784 + oh * 112 + ow * 4;
      float s = 0.f;
#pragma unroll
      for (int rr = 0; rr < 4; ++rr)
#pragma unroll
        for (int cc = 0; cc < 4; ++cc) s += xi[rr * 28 + cc];
      P[(h * 16 + img) * 56 + p] = s * (1.0f / 16.0f);
    }
    __syncthreads();
  }

  f32x4_t acc[2][2];
#pragma unroll
  for (int m = 0; m < 2; ++m)
#pragma unroll
    for (int n = 0; n < 2; ++n) acc[m][n] = (f32x4_t){0.f, 0.f, 0.f, 0.f};

  // ---- Phase B: layer-1, K=704 (22 k-frags: chunks 7,7,7,1) ----
  bf16x8_t q0[4], q1[4];
  if (cons) {
#pragma unroll
    for (int s = 0; s < 4; ++s) {
      q0[s] = *(const bf16x8_t*)(W1f + (size_t)(s * 16 + ntg0) * 512 + foff);
      q1[s] = *(const bf16x8_t*)(W1f + (size_t)(s * 16 + ntg0 + 1) * 512 + foff);
    }
  } else {
    kan_feats28(Ach0 + tr * 232 + ej * 14, P[tr * 56 + ej]);  // chunk 0
  }
  __syncthreads();
#pragma unroll
  for (int c = 0; c < 4; ++c) {
    const bf16* const Ac = (c & 1) ? Ach1 : Ach0;
    bf16* const An = (c & 1) ? Ach0 : Ach1;
    if (cons) {
      const int nks = (c < 3) ? 7 : 1;
#pragma unroll
      for (int ks = 0; ks < 7; ++ks) {
        if (ks >= nks) continue;
        const int kk = c * 7 + ks;
        const int sl = kk & 3;
        bf16x8_t bb0 = q0[sl], bb1 = q1[sl];
        if (kk + 4 < 22) {
          q0[sl] = *(const bf16x8_t*)(W1f + (size_t)((kk + 4) * 16 + ntg0) * 512 + foff);
          q1[sl] = *(const bf16x8_t*)(W1f + (size_t)((kk + 4) * 16 + ntg0 + 1) * 512 + foff);
        }
#pragma unroll
        for (int m = 0; m < 2; ++m) {
          bf16x8_t a = *(const bf16x8_t*)(Ac + (m * 16 + lr) * 232 + ks * 32 + quad * 8);
          acc[m][0] = __builtin_amdgcn_mfma_f32_16x16x32_bf16(a, bb0, acc[m][0], 0, 0, 0);
          acc[m][1] = __builtin_amdgcn_mfma_f32_16x16x32_bf16(a, bb1, acc[m][1], 0, 0, 0);
        }
      }
    } else {
      if (c < 2) {
        kan_feats28(An + tr * 232 + ej * 14, P[tr * 56 + (c + 1) * 16 + ej]);
      } else if (c == 2) {
        if (ej == 0) kan_feats28(An + tr * 232, P[tr * 56 + 48]);
        else if (ej == 1) {
          unsigned int* z = (unsigned int*)(An + tr * 232 + 14);
#pragma unroll
          for (int d = 0; d < 9; ++d) z[d] = 0u;  // pad k 686..703
        }
      }
    }
    __syncthreads();
  }
  // H1 = acc + b1 -> Hs (transposed); consumers cover all 256 cols
  if (cons) {
#pragma unroll
    for (int m = 0; m < 2; ++m)
#pragma unroll
      for (int n = 0; n < 2; ++n) {
        const int col = w * 32 + n * 16 + lr;
        const float bn = b1[col];
        f32x4_t v;
#pragma unroll
        for (int r = 0; r < 4; ++r) v[r] = acc[m][n][r] + bn;
        *(f32x4_t*)(Hs + col * 36 + m * 16 + quad * 4) = v;
      }
  }
  __syncthreads();

  // ---- Phase C: layer-2, K=3584 (16 chunks x 7 frags) ----
#pragma unroll
  for (int m = 0; m < 2; ++m)
#pragma unroll
    for (int n = 0; n < 2; ++n) acc[m][n] = (f32x4_t){0.f, 0.f, 0.f, 0.f};
  if (cons) {
#pragma unroll
    for (int s = 0; s < 4; ++s) {
      q0[s] = *(const bf16x8_t*)(W2f + (size_t)(s * 16 + ntg0) * 512 + foff);
      q1[s] = *(const bf16x8_t*)(W2f + (size_t)(s * 16 + ntg0 + 1) * 512 + foff);
    }
  } else {
    kan_feats28(Ach0 + tr * 232 + ej * 14, Hs[ej * 36 + tr]);  // chunk 0
  }
  __syncthreads();
#pragma unroll
  for (int c = 0; c < 16; ++c) {
    const bf16* const Ac = (c & 1) ? Ach1 : Ach0;
    bf16* const An = (c & 1) ? Ach0 : Ach1;
    if (cons) {
#pragma unroll
      for (int ks = 0; ks < 7; ++ks) {
        const int kk = c * 7 + ks;
        const int sl = kk & 3;
        bf16x8_t bb0 = q0[sl], bb1 = q1[sl];
        if (kk + 4 < 112) {
          q0[sl] = *(const bf16x8_t*)(W2f + (size_t)((kk + 4) * 16 + ntg0) * 512 + foff);
          q1[sl] = *(const bf16x8_t*)(W2f + (size_t)((kk + 4) * 16 + ntg0 + 1) * 512 + foff);
        }
#pragma unroll
        for (int m = 0; m < 2; ++m) {
          bf16x8_t a = *(const bf16x8_t*)(Ac + (m * 16 + lr) * 232 + ks * 32 + quad * 8);
          acc[m][0] = __builtin_amdgcn_mfma_f32_16x16x32_bf16(a, bb0, acc[m][0], 0, 0, 0);
          acc[m][1] = __builtin_amdgcn_mfma_f32_16x16x32_bf16(a, bb1, acc[m][1], 0, 0, 0);
        }
      }
    } else if (c < 15) {
      kan_feats28(An + tr * 232 + ej * 14, Hs[((c + 1) * 16 + ej) * 36 + tr]);
    }
    __syncthreads();
  }
  // H2 = acc + b2 -> Hs (overwrite; H1 dead after chunk-15 feats)
  if (cons) {
#pragma unroll
    for (int m = 0; m < 2; ++m)
#pragma unroll
      for (int n = 0; n < 2; ++n) {
        const int col = w * 32 + n * 16 + lr;
        const float bn = b2[col];
        f32x4_t v;
#pragma unroll
        for (int r = 0; r < 4; ++r) v[r] = acc[m][n][r] + bn;
        *(f32x4_t*)(Hs + col * 36 + m * 16 + quad * 4) = v;
      }
  }
  __syncthreads();

  // ---- Phase E: layer-3 (N=16, 10 real). Consumers = waves 0..6 (one ks
  //      each, both m-halves); producers = waves 8..15. ----
  f32x4_t acc3[2];
  acc3[0] = (f32x4_t){0.f, 0.f, 0.f, 0.f};
  acc3[1] = acc3[0];
  bf16x8_t q3[4];
  if (w < 7) {
#pragma unroll
    for (int s = 0; s < 4; ++s)
      q3[s] = *(const bf16x8_t*)(W3f + (size_t)(s * 7 + w) * 512 + foff);
  } else if (!cons) {
    kan_feats28(Ach0 + tr * 232 + ej * 14, Hs[ej * 36 + tr]);  // chunk 0
  }
  __syncthreads();
#pragma unroll
  for (int c = 0; c < 16; ++c) {
    const bf16* const Ac = (c & 1) ? Ach1 : Ach0;
    bf16* const An = (c & 1) ? Ach0 : Ach1;
    if (w < 7) {
      bf16x8_t bb = q3[c & 3];
      if (c + 4 < 16)
        q3[c & 3] = *(const bf16x8_t*)(W3f + (size_t)((c + 4) * 7 + w) * 512 + foff);
#pragma unroll
      for (int m = 0; m < 2; ++m) {
        bf16x8_t a = *(const bf16x8_t*)(Ac + (m * 16 + lr) * 232 + w * 32 + quad * 8);
        acc3[m] = __builtin_amdgcn_mfma_f32_16x16x32_bf16(a, bb, acc3[m], 0, 0, 0);
      }
    } else if (!cons && c < 15) {
      kan_feats28(An + tr * 232 + ej * 14, Hs[((c + 1) * 16 + ej) * 36 + tr]);
    }
    __syncthreads();
  }
  if (w < 7) {
#pragma unroll
    for (int m = 0; m < 2; ++m)
#pragma unroll
      for (int r = 0; r < 4; ++r)
        Red[w * 512 + (m * 16 + quad * 4 + r) * 16 + lr] = acc3[m][r];
  }
  __syncthreads();
  if (t < 512) {
    float s = (ej < 10) ? b3[ej] : 0.f;
#pragma unroll
    for (int ks = 0; ks < 7; ++ks) s += Red[ks * 512 + tr * 16 + ej];
    V[tr * 16 + ej] = s;
  }
  __syncthreads();
  if (t < 32) {
    float vv[10];
#pragma unroll
    for (int o = 0; o < 10; ++o) vv[o] = V[t * 16 + o];
    float mx = vv[0];
#pragma unroll
    for (int o = 1; o < 10; ++o) mx = fmaxf(mx, vv[o]);
    float se = 0.f;
#pragma unroll
    for (int o = 0; o < 10; ++o) se += expf(vv[o] - mx);
    const float l = mx + logf(se);
#pragma unroll
    for (int o = 0; o < 10; ++o) out[(size_t)(r0 + t) * 10 + o] = vv[o] - l;
  }
}

extern "C" void kernel_launch(void* const* d_in, const int* in_sizes, int n_in,
                              void* d_out, int out_size, void* d_ws, size_t ws_size,
                              hipStream_t stream) {
  const float* x = (const float*)d_in[0];
  const float* coef1 = (const float*)d_in[1];
  const float* sb1 = (const float*)d_in[2];
  const float* sp1 = (const float*)d_in[3];
  const float* b1 = (const float*)d_in[4];
  const float* coef2 = (const float*)d_in[5];
  const float* sb2 = (const float*)d_in[6];
  const float* sp2 = (const float*)d_in[7];
  const float* b2 = (const float*)d_in[8];
  const float* coef3 = (const float*)d_in[9];
  const float* sb3 = (const float*)d_in[10];
  const float* sp3 = (const float*)d_in[11];
  const float* b3 = (const float*)d_in[12];
  float* out = (float*)d_out;

  char* ws = (char*)d_ws;
  bf16* W1f = (bf16*)ws;              // 22 frags x 16 ntg x 1KB = 360448 B
  bf16* W2f = (bf16*)(ws + 360448);   // 112 x 16 x 1KB = 1835008 B
  bf16* W3f = (bf16*)(ws + 2195456);  // 112 x 1KB = 114688 B

  prep_all<<<818, 256, 0, stream>>>(coef1, sb1, sp1, coef2, sb2, sp2,
                                    coef3, sb3, sp3, W1f, W2f, W3f);
  meganet<<<256, 1024, 0, stream>>>(x, W1f, W2f, W3f, b1, b2, b3, out);
}